// Round 2
// baseline (2600.801 us; speedup 1.0000x reference)
//
#include <hip/hip_runtime.h>

typedef _Float16 f16x8 __attribute__((ext_vector_type(8)));
typedef float f32x4 __attribute__((ext_vector_type(4)));

constexpr int kT = 1024;    // tokens per batch
constexpr int kD = 1024;    // model dim
// rows total = B*T = 2048

__device__ __forceinline__ void st_f16x4(_Float16* p, float4 v) {
  union { _Float16 h[4]; unsigned long long u; } u;
  u.h[0] = (_Float16)v.x; u.h[1] = (_Float16)v.y;
  u.h[2] = (_Float16)v.z; u.h[3] = (_Float16)v.w;
  *reinterpret_cast<unsigned long long*>(p) = u.u;
}

// ---------------- embedding gather ----------------
__global__ void embed_kernel(const int* __restrict__ tok, const float* __restrict__ W,
                             float* __restrict__ X) {
  const int row = blockIdx.x;
  const int tk = tok[row];
  reinterpret_cast<float4*>(X + (size_t)row * kD)[threadIdx.x] =
      reinterpret_cast<const float4*>(W + (size_t)tk * kD)[threadIdx.x];
}

// ---------------- RMSNorm (f32 in/out) ----------------
__global__ __launch_bounds__(256) void rmsnorm_kernel(const float* __restrict__ X,
                                                      const float* __restrict__ w,
                                                      float* __restrict__ O) {
  const int row = blockIdx.x;
  const float4 v = reinterpret_cast<const float4*>(X + (size_t)row * kD)[threadIdx.x];
  float ss = v.x * v.x + v.y * v.y + v.z * v.z + v.w * v.w;
#pragma unroll
  for (int mk = 1; mk < 64; mk <<= 1) ss += __shfl_xor(ss, mk);
  __shared__ float red[4];
  if ((threadIdx.x & 63) == 0) red[threadIdx.x >> 6] = ss;
  __syncthreads();
  const float tot = red[0] + red[1] + red[2] + red[3];
  const float sc = rsqrtf(tot * (1.0f / kD) + 1e-6f);
  const float4 wv = reinterpret_cast<const float4*>(w)[threadIdx.x];
  float4 o;
  o.x = v.x * sc * wv.x; o.y = v.y * sc * wv.y;
  o.z = v.z * sc * wv.z; o.w = v.w * sc * wv.w;
  reinterpret_cast<float4*>(O + (size_t)row * kD)[threadIdx.x] = o;
}

// ---------------- GEMM: C[M,N] = A[M,K] * B[N,K]^T + bias (+Res), f32 io, f16 MFMA ----
template <int RES>
__global__ __launch_bounds__(256) void gemm_bt(const float* __restrict__ A,
                                               const float* __restrict__ B,
                                               const float* __restrict__ bias,
                                               const float* __restrict__ Res,
                                               float* __restrict__ C,
                                               int M, int N, int K) {
  __shared__ _Float16 As[128 * 72];
  __shared__ _Float16 Bs[128 * 72];
  const int t = threadIdx.x;
  const int lane = t & 63, wid = t >> 6;
  const int wr = wid >> 1, wc = wid & 1;
  const int l15 = lane & 15, l4 = lane >> 4;
  const int rowA0 = blockIdx.y * 128, rowB0 = blockIdx.x * 128;
  const int lr = t >> 4, lc = (t & 15) * 4;
  f32x4 acc[4][4] = {};
  for (int k0 = 0; k0 < K; k0 += 64) {
    __syncthreads();
#pragma unroll
    for (int p = 0; p < 8; ++p) {
      const int r = lr + p * 16;
      const float4 av = *reinterpret_cast<const float4*>(A + (size_t)(rowA0 + r) * K + k0 + lc);
      const float4 bv = *reinterpret_cast<const float4*>(B + (size_t)(rowB0 + r) * K + k0 + lc);
      st_f16x4(&As[r * 72 + lc], av);
      st_f16x4(&Bs[r * 72 + lc], bv);
    }
    __syncthreads();
#pragma unroll
    for (int ks = 0; ks < 2; ++ks) {
      const int ko = ks * 32 + l4 * 8;
      f16x8 af[4], bf[4];
#pragma unroll
      for (int m = 0; m < 4; ++m)
        af[m] = *reinterpret_cast<const f16x8*>(&As[(wr * 64 + m * 16 + l15) * 72 + ko]);
#pragma unroll
      for (int n = 0; n < 4; ++n)
        bf[n] = *reinterpret_cast<const f16x8*>(&Bs[(wc * 64 + n * 16 + l15) * 72 + ko]);
#pragma unroll
      for (int m = 0; m < 4; ++m)
#pragma unroll
        for (int n = 0; n < 4; ++n)
          acc[m][n] = __builtin_amdgcn_mfma_f32_16x16x32_f16(af[m], bf[n], acc[m][n], 0, 0, 0);
    }
  }
  const int cr0 = rowA0 + wr * 64, cc0 = rowB0 + wc * 64;
#pragma unroll
  for (int m = 0; m < 4; ++m)
#pragma unroll
    for (int n = 0; n < 4; ++n) {
      const int col = cc0 + n * 16 + l15;
      const float bb = bias[col];
#pragma unroll
      for (int r = 0; r < 4; ++r) {
        const int row = cr0 + m * 16 + l4 * 4 + r;
        float v = acc[m][n][r] + bb;
        if (RES) v += Res[(size_t)row * N + col];
        C[(size_t)row * N + col] = v;
      }
    }
}

// ---------------- RoPE (in-place, f32) ----------------
__global__ void rope_kernel(float* __restrict__ X, int nh, int total) {
  const int i = blockIdx.x * 256 + threadIdx.x;
  if (i >= total) return;
  const int ppr = nh * 32;
  const int row = i / ppr;
  const int rem = i - row * ppr;
  const int hh = rem >> 5, pi = rem & 31;
  const int tpos = row & (kT - 1);
  const float freq = expf(-0.28782313662425572f * (float)pi);  // 10000^(-pi/32)
  const float ang = (float)tpos * freq;
  float s, c;
  sincosf(ang, &s, &c);
  float* p = X + (size_t)row * (nh * 64) + hh * 64 + pi;
  const float x1 = p[0], x2 = p[32];
  p[0] = x1 * c - x2 * s;
  p[32] = x2 * c + x1 * s;
}

// ---------------- causal GQA flash attention ----------------
// grid = (B*HQ=32, T/64=16), 256 threads (4 waves x 16 q-rows)
__global__ __launch_bounds__(256) void attn_kernel(const float* __restrict__ Q,
                                                   const float* __restrict__ K,
                                                   const float* __restrict__ V,
                                                   float* __restrict__ O) {
  __shared__ _Float16 Ks[64 * 72];
  __shared__ _Float16 VT[64 * 72];
  __shared__ _Float16 Ps[4][16 * 72];
  const int bh = blockIdx.x;
  const int b = bh >> 4, h = bh & 15, kvh = h >> 2;
  const int qt = blockIdx.y;
  const int t = threadIdx.x, lane = t & 63, wid = t >> 6;
  const int l15 = lane & 15, l4 = lane >> 4;

  f16x8 qf[2];
  {
    const float* qp = Q + (size_t)(b * kT + qt * 64 + wid * 16 + l15) * 1024 + h * 64 + l4 * 8;
#pragma unroll
    for (int ks = 0; ks < 2; ++ks) {
      const float4 f0 = *reinterpret_cast<const float4*>(qp + ks * 32);
      const float4 f1 = *reinterpret_cast<const float4*>(qp + ks * 32 + 4);
      union { _Float16 h[8]; f16x8 v; } u;
      u.h[0] = (_Float16)f0.x; u.h[1] = (_Float16)f0.y; u.h[2] = (_Float16)f0.z; u.h[3] = (_Float16)f0.w;
      u.h[4] = (_Float16)f1.x; u.h[5] = (_Float16)f1.y; u.h[6] = (_Float16)f1.z; u.h[7] = (_Float16)f1.w;
      qf[ks] = u.v;
    }
  }
  f32x4 ctx[4] = {};
  float mrow[4], lrow[4];
#pragma unroll
  for (int r = 0; r < 4; ++r) { mrow[r] = -1e30f; lrow[r] = 0.f; }

  const int sr = t >> 4;
  const int sc = (t & 15) * 4;

  for (int j = 0; j <= qt; ++j) {
    __syncthreads();
#pragma unroll
    for (int p = 0; p < 4; ++p) {
      const int kr = sr + p * 16;
      const float4 kv4 = *reinterpret_cast<const float4*>(
          K + (size_t)(b * kT + j * 64 + kr) * 256 + kvh * 64 + sc);
      st_f16x4(&Ks[kr * 72 + sc], kv4);
      const float4 vv4 = *reinterpret_cast<const float4*>(
          V + (size_t)(b * kT + j * 64 + kr) * 256 + kvh * 64 + sc);
      VT[(sc + 0) * 72 + kr] = (_Float16)vv4.x;
      VT[(sc + 1) * 72 + kr] = (_Float16)vv4.y;
      VT[(sc + 2) * 72 + kr] = (_Float16)vv4.z;
      VT[(sc + 3) * 72 + kr] = (_Float16)vv4.w;
    }
    __syncthreads();

    f32x4 s[4] = {};
#pragma unroll
    for (int ks = 0; ks < 2; ++ks) {
      const int ko = ks * 32 + l4 * 8;
#pragma unroll
      for (int n = 0; n < 4; ++n) {
        const f16x8 kf = *reinterpret_cast<const f16x8*>(&Ks[(n * 16 + l15) * 72 + ko]);
        s[n] = __builtin_amdgcn_mfma_f32_16x16x32_f16(qf[ks], kf, s[n], 0, 0, 0);
      }
    }

    const int q0 = qt * 64 + wid * 16 + l4 * 4;
    const int kc = j * 64 + l15;
    float p4[4][4];
#pragma unroll
    for (int r = 0; r < 4; ++r) {
      float mx = -1e30f;
#pragma unroll
      for (int n = 0; n < 4; ++n) {
        float v = s[n][r] * 0.125f;
        if (kc + n * 16 > q0 + r) v = -1e9f;
        p4[r][n] = v;
        mx = fmaxf(mx, v);
      }
#pragma unroll
      for (int mk = 1; mk < 16; mk <<= 1) mx = fmaxf(mx, __shfl_xor(mx, mk));
      const float mnew = fmaxf(mrow[r], mx);
      const float sf = expf(mrow[r] - mnew);
      mrow[r] = mnew;
      float rs = 0.f;
#pragma unroll
      for (int n = 0; n < 4; ++n) {
        const float pv = expf(p4[r][n] - mnew);
        p4[r][n] = pv;
        rs += pv;
      }
#pragma unroll
      for (int mk = 1; mk < 16; mk <<= 1) rs += __shfl_xor(rs, mk);
      lrow[r] = lrow[r] * sf + rs;
#pragma unroll
      for (int dt = 0; dt < 4; ++dt) ctx[dt][r] *= sf;
    }

    _Float16* pw = &Ps[wid][0];
#pragma unroll
    for (int r = 0; r < 4; ++r)
#pragma unroll
      for (int n = 0; n < 4; ++n)
        pw[(l4 * 4 + r) * 72 + n * 16 + l15] = (_Float16)p4[r][n];

#pragma unroll
    for (int ks = 0; ks < 2; ++ks) {
      const int ko = ks * 32 + l4 * 8;
      const f16x8 pf = *reinterpret_cast<const f16x8*>(&pw[l15 * 72 + ko]);
#pragma unroll
      for (int dt = 0; dt < 4; ++dt) {
        const f16x8 vf = *reinterpret_cast<const f16x8*>(&VT[(dt * 16 + l15) * 72 + ko]);
        ctx[dt] = __builtin_amdgcn_mfma_f32_16x16x32_f16(pf, vf, ctx[dt], 0, 0, 0);
      }
    }
  }

#pragma unroll
  for (int dt = 0; dt < 4; ++dt)
#pragma unroll
    for (int r = 0; r < 4; ++r) {
      const int qrow = qt * 64 + wid * 16 + l4 * 4 + r;
      O[(size_t)(b * kT + qrow) * 1024 + h * 64 + dt * 16 + l15] = ctx[dt][r] / lrow[r];
    }
}

// ---------------- silu(g)*u ----------------
__global__ void silu_mul_kernel(float* __restrict__ G, const float* __restrict__ U, int n4) {
  const int i = blockIdx.x * 256 + threadIdx.x;
  if (i >= n4) return;
  float4 g = reinterpret_cast<float4*>(G)[i];
  const float4 u = reinterpret_cast<const float4*>(U)[i];
  g.x = g.x / (1.f + expf(-g.x)) * u.x;
  g.y = g.y / (1.f + expf(-g.y)) * u.y;
  g.z = g.z / (1.f + expf(-g.z)) * u.z;
  g.w = g.w / (1.f + expf(-g.w)) * u.w;
  reinterpret_cast<float4*>(G)[i] = g;
}

extern "C" void kernel_launch(void* const* d_in, const int* in_sizes, int n_in,
                              void* d_out, int out_size, void* d_ws, size_t ws_size,
                              hipStream_t stream) {
  const int* tokens = (const int*)d_in[0];
  const float* embed_W = (const float*)d_in[1];
  const float* q_w = (const float*)d_in[2];
  const float* q_b = (const float*)d_in[3];
  const float* k_w = (const float*)d_in[4];
  const float* k_b = (const float*)d_in[5];
  const float* v_w = (const float*)d_in[6];
  const float* v_b = (const float*)d_in[7];
  const float* o_w = (const float*)d_in[8];
  const float* o_b = (const float*)d_in[9];
  const float* anw = (const float*)d_in[10];
  const float* mnw = (const float*)d_in[11];
  const float* gate_w = (const float*)d_in[12];
  const float* gate_b = (const float*)d_in[13];
  const float* up_w = (const float*)d_in[14];
  const float* up_b = (const float*)d_in[15];
  const float* down_w = (const float*)d_in[16];
  const float* down_b = (const float*)d_in[17];
  const float* norm_w = (const float*)d_in[18];
  const float* head_w = (const float*)d_in[19];
  const float* head_b = (const float*)d_in[20];
  float* out = (float*)d_out;

  // scratch layout: big intermediates live in d_out (fully overwritten by head GEMM at the end)
  float* G = out;                       // 2048*4096
  float* U = G + (size_t)2048 * 4096;   // 2048*4096
  float* X = U + (size_t)2048 * 4096;   // 2048*1024 residual stream
  float* Qb = X + (size_t)2048 * 1024;  // 2048*1024
  float* Kb = Qb + (size_t)2048 * 1024; // 2048*256
  float* Vb = Kb + (size_t)2048 * 256;  // 2048*256
  float* CTX = Vb + (size_t)2048 * 256; // 2048*1024
  float* H = (float*)d_ws;              // 2048*1024 (8.4 MB in ws)

  embed_kernel<<<2048, 256, 0, stream>>>(tokens, embed_W, X);

  for (int l = 0; l < 4; ++l) {
    rmsnorm_kernel<<<2048, 256, 0, stream>>>(X, anw + l * 1024, H);
    gemm_bt<0><<<dim3(8, 16), 256, 0, stream>>>(H, q_w + (size_t)l * 1024 * 1024,
                                                q_b + l * 1024, nullptr, Qb, 2048, 1024, 1024);
    gemm_bt<0><<<dim3(2, 16), 256, 0, stream>>>(H, k_w + (size_t)l * 256 * 1024,
                                                k_b + l * 256, nullptr, Kb, 2048, 256, 1024);
    gemm_bt<0><<<dim3(2, 16), 256, 0, stream>>>(H, v_w + (size_t)l * 256 * 1024,
                                                v_b + l * 256, nullptr, Vb, 2048, 256, 1024);
    rope_kernel<<<(2048 * 512 + 255) / 256, 256, 0, stream>>>(Qb, 16, 2048 * 512);
    rope_kernel<<<(2048 * 128 + 255) / 256, 256, 0, stream>>>(Kb, 4, 2048 * 128);
    attn_kernel<<<dim3(32, 16), 256, 0, stream>>>(Qb, Kb, Vb, CTX);
    gemm_bt<1><<<dim3(8, 16), 256, 0, stream>>>(CTX, o_w + (size_t)l * 1024 * 1024,
                                                o_b + l * 1024, X, X, 2048, 1024, 1024);
    rmsnorm_kernel<<<2048, 256, 0, stream>>>(X, mnw + l * 1024, H);
    gemm_bt<0><<<dim3(32, 16), 256, 0, stream>>>(H, gate_w + (size_t)l * 4096 * 1024,
                                                 gate_b + l * 4096, nullptr, G, 2048, 4096, 1024);
    gemm_bt<0><<<dim3(32, 16), 256, 0, stream>>>(H, up_w + (size_t)l * 4096 * 1024,
                                                 up_b + l * 4096, nullptr, U, 2048, 4096, 1024);
    silu_mul_kernel<<<(2048 * 1024 + 255) / 256, 256, 0, stream>>>(G, U, 2048 * 1024);
    gemm_bt<1><<<dim3(8, 16), 256, 0, stream>>>(G, down_w + (size_t)l * 1024 * 4096,
                                                down_b + l * 1024, X, X, 2048, 1024, 4096);
  }

  rmsnorm_kernel<<<2048, 256, 0, stream>>>(X, norm_w, H);
  gemm_bt<0><<<dim3(250, 16), 256, 0, stream>>>(H, head_w, head_b, nullptr, out,
                                                2048, 32000, 1024);
}